// Round 15
// baseline (529.709 us; speedup 1.0000x reference)
//
#include <hip/hip_runtime.h>

#define N_NODES 10000
#define N_EDGES 100000
#define IN_CH 64
#define EDGE_DIM 16
#define HID 128
#define HEADS 4
#define HC 512          // HEADS*HID
#define LAYERS 4
#define NUM_GRAPHS 256
#define NCAT 1152       // 512(xl) + 512(xr) + 128(res) packed cols
#define LDPK 72         // padded LDS stride for 64-elem K-chunk (bf16 elems)

#define PREP_BLOCKS 320 // 10 * LAYERS * 8
#define DEG_BLOCKS 782  // ceil(N_EDGES/128)

typedef __bf16 bf16;
typedef __bf16 bf16x8 __attribute__((ext_vector_type(8)));
typedef __bf16 bf16x4 __attribute__((ext_vector_type(4)));
typedef float floatx4 __attribute__((ext_vector_type(4)));
typedef _Float16 f16;
typedef _Float16 f16x2 __attribute__((ext_vector_type(2)));

__device__ __forceinline__ float elu_f(float x) { return x > 0.f ? x : (__expf(x) - 1.f); }

// ---------------- merged prep: weight repack + degree/count + h0 ----------------
__global__ __launch_bounds__(128) void k_prep_all(
    const float* __restrict__ Wl, const float* __restrict__ bl,
    const float* __restrict__ Wr, const float* __restrict__ br,
    const float* __restrict__ Wres, const float* __restrict__ bres,
    const float* __restrict__ We,
    bf16* __restrict__ WT, float* __restrict__ bcat, f16* __restrict__ WeH,
    const int* __restrict__ ei, const int* __restrict__ batch,
    int* __restrict__ deg, int* __restrict__ cnt,
    const float* __restrict__ x, const float* __restrict__ Win,
    const float* __restrict__ b_in, bf16* __restrict__ h_bf) {
    __shared__ float smem[16 * 129];
    int b = blockIdx.x;
    int t = threadIdx.x;

    if (b < PREP_BLOCKS) {
        int nt = b % 10, i = (b / 10) % LAYERS, z = b / 40;
        if (nt == 9) {
            if (z < 4) {
                int c = z * 128 + t;
                const float* src = We + (size_t)i * EDGE_DIM * HC + c;
                f16 buf[16];
#pragma unroll
                for (int k = 0; k < EDGE_DIM; k++) buf[k] = (f16)src[(size_t)k * HC];
                f16* dst = WeH + ((size_t)i * HC + c) * EDGE_DIM;
                *(uint4*)dst = *(uint4*)buf;
                *(uint4*)(dst + 8) = *(uint4*)(buf + 8);
            }
            return;
        }
        float (*tile)[129] = (float(*)[129])smem;
        int n0 = nt * 128;
        const float* base = nullptr; const float* bsrc = nullptr; int ld = 0;
        if (nt < 4)       { base = Wl + (size_t)i * HID * HC + n0;          bsrc = bl + i * HC + n0;              ld = HC; }
        else if (nt < 8)  { base = Wr + (size_t)i * HID * HC + (n0 - 512);  bsrc = br + i * HC + (n0 - 512);      ld = HC; }
        else if (i > 0)   { base = Wres + (size_t)(i - 1) * HID * HID;      bsrc = bres + (size_t)(i - 1) * HID;  ld = HID; }
        if (base) {
#pragma unroll
            for (int r = 0; r < 16; r++) tile[r][t] = base[(size_t)(z * 16 + r) * ld + t];
        } else {
#pragma unroll
            for (int r = 0; r < 16; r++) tile[r][t] = 0.f;
        }
        __syncthreads();
        int n = n0 + t;
        if (z == 0) bcat[(size_t)i * NCAT + n] = base ? bsrc[t] : 0.f;
        bf16* dst = WT + ((size_t)i * NCAT + n) * HID + z * 16;
#pragma unroll
        for (int kc = 0; kc < 2; kc++) {
            bf16x8 v;
#pragma unroll
            for (int u = 0; u < 8; u++) v[u] = (bf16)tile[kc * 8 + u][t];
            *(bf16x8*)(dst + kc * 8) = v;
        }
    } else if (b < PREP_BLOCKS + DEG_BLOCKS) {
        int e = (b - PREP_BLOCKS) * 128 + t;
        if (e < N_EDGES) atomicAdd(&deg[ei[N_EDGES + e]], 1);
        if (e < N_NODES) atomicAdd(&cnt[batch[e]], 1);
    } else {
        int n = b - (PREP_BLOCKS + DEG_BLOCKS);
        float* xs = smem;
        if (t < IN_CH) xs[t] = x[(size_t)n * IN_CH + t];
        __syncthreads();
        float s = b_in[t];
#pragma unroll 8
        for (int k = 0; k < IN_CH; k++) s = fmaf(xs[k], Win[k * HID + t], s);
        h_bf[(size_t)n * HID + t] = (bf16)elu_f(s);
    }
}

// ---------------- MFMA bf16 GEMM: C[M,NCAT] = A[M,128] @ WT^T + bias ------
__global__ __launch_bounds__(256) void k_gemm_mfma(
    const bf16* __restrict__ A, const bf16* __restrict__ WT,
    const float* __restrict__ bcat, bf16* __restrict__ C, int M) {
    __shared__ __align__(16) unsigned short As[128 * LDPK];
    __shared__ __align__(16) unsigned short Bs[128 * LDPK];
    int t = threadIdx.x;
    int r0 = blockIdx.x * 128, c0 = blockIdx.y * 128;

    int wave = t >> 6, lane = t & 63;
    int wm = wave & 1, wn = wave >> 1;
    int quad = lane >> 4, lm = lane & 15;
    floatx4 zero = {0.f, 0.f, 0.f, 0.f};
    floatx4 acc[4][4];
#pragma unroll
    for (int mi = 0; mi < 4; mi++)
#pragma unroll
        for (int ni = 0; ni < 4; ni++) acc[mi][ni] = zero;

    const unsigned short* Ab = &As[(wm * 64 + lm) * LDPK + quad * 8];
    const unsigned short* Bb = &Bs[(wn * 64 + lm) * LDPK + quad * 8];

    for (int kc = 0; kc < 2; kc++) {
#pragma unroll
        for (int i = 0; i < 4; i++) {
            int idx = t + i * 256;
            int row = idx >> 3;
            int ch = idx & 7;
            int r = r0 + row; if (r >= M) r = M - 1;
            *(uint4*)&As[row * LDPK + ch * 8] =
                *(const uint4*)(A + (size_t)r * HID + kc * 64 + ch * 8);
            *(uint4*)&Bs[row * LDPK + ch * 8] =
                *(const uint4*)(WT + (size_t)(c0 + row) * HID + kc * 64 + ch * 8);
        }
        __syncthreads();
#pragma unroll
        for (int ks = 0; ks < 2; ks++) {
            bf16x8 af[4], bfr[4];
#pragma unroll
            for (int mi = 0; mi < 4; mi++) af[mi] = *(const bf16x8*)(Ab + mi * 16 * LDPK + ks * 32);
#pragma unroll
            for (int ni = 0; ni < 4; ni++) bfr[ni] = *(const bf16x8*)(Bb + ni * 16 * LDPK + ks * 32);
#pragma unroll
            for (int mi = 0; mi < 4; mi++)
#pragma unroll
                for (int ni = 0; ni < 4; ni++)
                    acc[mi][ni] = __builtin_amdgcn_mfma_f32_16x16x32_bf16(bfr[ni], af[mi], acc[mi][ni], 0, 0, 0);
        }
        __syncthreads();
    }

#pragma unroll
    for (int mi = 0; mi < 4; mi++) {
        int row = r0 + wm * 64 + mi * 16 + lm;
        if (row < M) {
            bf16* crow = C + (size_t)row * NCAT;
#pragma unroll
            for (int ni = 0; ni < 4; ni++) {
                int cb = c0 + wn * 64 + ni * 16 + quad * 4;
                float4 b4 = *(const float4*)(bcat + cb);
                floatx4 v = acc[mi][ni];
                bf16x4 o = {(bf16)(v[0] + b4.x), (bf16)(v[1] + b4.y),
                            (bf16)(v[2] + b4.z), (bf16)(v[3] + b4.w)};
                *(bf16x4*)(crow + cb) = o;
            }
        }
    }
}

// shfl-based scan, 4 elems/thread + degree-descending node order (counting sort)
__global__ __launch_bounds__(1024) void k_scan(const int* __restrict__ deg,
                                               int* __restrict__ row_start,
                                               int* __restrict__ cursor,
                                               int* __restrict__ order) {
    __shared__ int wsum[16];
    __shared__ int carry_s;
    __shared__ int hist[64];
    __shared__ int binoff[64];
    int t = threadIdx.x;
    int wave = t >> 6, lane = t & 63;
    if (t == 0) { carry_s = 0; row_start[0] = 0; }
    __syncthreads();
    for (int base = 0; base < N_NODES; base += 4096) {
        int i0 = base + t * 4;
        int v[4];
#pragma unroll
        for (int u = 0; u < 4; u++) v[u] = (i0 + u < N_NODES) ? deg[i0 + u] : 0;
        int tsum = v[0] + v[1] + v[2] + v[3];
        int incl = tsum;
#pragma unroll
        for (int off = 1; off < 64; off <<= 1) {
            int u = __shfl_up(incl, off, 64);
            if (lane >= off) incl += u;
        }
        if (lane == 63) wsum[wave] = incl;
        __syncthreads();
        if (wave == 0) {
            int ws = (lane < 16) ? wsum[lane] : 0;
#pragma unroll
            for (int off = 1; off < 16; off <<= 1) {
                int u = __shfl_up(ws, off, 64);
                if (lane >= off) ws += u;
            }
            if (lane < 16) wsum[lane] = ws;
        }
        __syncthreads();
        int carry = carry_s;
        int chunk_total = wsum[15];
        int p = carry + ((wave == 0) ? 0 : wsum[wave - 1]) + incl - tsum;
#pragma unroll
        for (int u = 0; u < 4; u++) {
            int i = i0 + u;
            if (i < N_NODES) { cursor[i] = p; p += v[u]; row_start[i + 1] = p; }
        }
        __syncthreads();
        if (t == 0) carry_s = carry + chunk_total;
    }

    // ---- counting sort of nodes by degree, DESCENDING (high degree first) ----
    if (t < 64) hist[t] = 0;
    __syncthreads();
    for (int i = t; i < N_NODES; i += 1024) {
        int d = deg[i]; if (d > 63) d = 63;
        atomicAdd(&hist[d], 1);
    }
    __syncthreads();
    if (t < 64) {                       // wave 0 only: suffix sums over 64 bins
        int s = hist[t];
#pragma unroll
        for (int off = 1; off < 64; off <<= 1) {
            int u = __shfl_down(s, off, 64);
            if (t + off >= 64) u = 0;
            s += u;
        }
        binoff[t] = s - hist[t];        // Σ of strictly-greater bins
    }
    __syncthreads();
    for (int i = t; i < N_NODES; i += 1024) {
        int d = deg[i]; if (d > 63) d = 63;
        int pos = atomicAdd(&binoff[d], 1);
        order[pos] = i;
    }
}

// scatter edges into CSR order; permute + f16-convert edge_attr
__global__ void k_scatter(const int* __restrict__ ei, const float* __restrict__ edge_attr,
                          int* __restrict__ cursor,
                          int* __restrict__ ssrc, f16* __restrict__ ea_h) {
    int e = blockIdx.x * blockDim.x + threadIdx.x;
    if (e < N_EDGES) {
        int d = ei[N_EDGES + e];
        int pos = atomicAdd(&cursor[d], 1);
        ssrc[pos] = ei[e];
        const float* s = edge_attr + (size_t)e * EDGE_DIM;
        f16 buf[16];
#pragma unroll
        for (int q = 0; q < 16; q++) buf[q] = (f16)s[q];
        f16* dst = ea_h + (size_t)pos * EDGE_DIM;
        *(uint4*)dst = *(uint4*)buf;
        *(uint4*)(dst + 8) = *(uint4*)(buf + 8);
    }
}

// ---------------- fused edge phase: edges SPLIT across the 2 waves ----------
// Each wave covers all 512 ch (8 ch/lane, head=lane>>4, 4-shfl reduce over 16
// lanes). wave0 = even CSR slots, wave1 = odd. Per-edge loads/shfl/exp issued
// ONCE (R14 duplicated them across both waves) and per-wave trip count halves.
// Partial (l, acc) merged once per node via 4KB LDS (order-independent sums).
__device__ __forceinline__ void edge_body8(
    int j, const int* __restrict__ ssrc, const f16* __restrict__ ea_h,
    const bf16* __restrict__ xlr, int c0, const f16x2* __restrict__ wr,
    const float* xr, const float* attc, float& lsum, float* acc) {
    int s = ssrc[j];
    const f16x2* eah = (const f16x2*)(ea_h + (size_t)j * EDGE_DIM);
    f16x2 ep[8];
#pragma unroll
    for (int kp = 0; kp < 8; kp++) ep[kp] = eah[kp];
    bf16x8 vl = *(const bf16x8*)(xlr + (size_t)s * NCAT + c0);
    float part = 0.f;
    float x[8];
#pragma unroll
    for (int c = 0; c < 8; c++) {
        float ec = 0.f;
#pragma unroll
        for (int kp = 0; kp < 8; kp++)
            ec = __builtin_amdgcn_fdot2(wr[c * 8 + kp], ep[kp], ec, false);
        x[c] = (float)vl[c];
        float m = x[c] + xr[c] + ec;
        m = fmaxf(m, 0.2f * m);
        part = fmaf(m, attc[c], part);
    }
#pragma unroll
    for (int off = 1; off < 16; off <<= 1) part += __shfl_xor(part, off, 64);
    float p = __expf(part);
    lsum += p;
#pragma unroll
    for (int c = 0; c < 8; c++) acc[c] = fmaf(p, x[c], acc[c]);
}

__global__ __launch_bounds__(128) void k_edge_fused(
    const bf16* __restrict__ xlr, const f16* __restrict__ ea_h,
    const int* __restrict__ row_start, const int* __restrict__ ssrc,
    const int* __restrict__ order,
    const f16* __restrict__ WeH_l, const float* __restrict__ att_l,
    const float* __restrict__ bgat_l, const float* __restrict__ gamma_l,
    const float* __restrict__ beta_l,
    int has_res,
    const int* __restrict__ batch, float* __restrict__ hsum, int do_pool,
    bf16* __restrict__ hbf_out) {
    int t = threadIdx.x;
    int wave = t >> 6;
    int lane = t & 63;
    int n = order[blockIdx.x];
    int c0 = lane * 8;               // channel base within 512
    int head = lane >> 4;            // 16 lanes per head
    int ca = (lane & 15) * 8;        // channel within head (0..120)

    const f16x2* wr = (const f16x2*)(WeH_l + (size_t)c0 * EDGE_DIM); // 256B contiguous
    float attc[8], xr[8];
    {
        float4 aA = *(const float4*)(att_l + head * HID + ca);
        float4 aB = *(const float4*)(att_l + head * HID + ca + 4);
        attc[0] = aA.x; attc[1] = aA.y; attc[2] = aA.z; attc[3] = aA.w;
        attc[4] = aB.x; attc[5] = aB.y; attc[6] = aB.z; attc[7] = aB.w;
        bf16x8 vr8 = *(const bf16x8*)(xlr + (size_t)n * NCAT + 512 + c0);
#pragma unroll
        for (int c = 0; c < 8; c++) xr[c] = (float)vr8[c];
    }

    int e0 = row_start[n], e1 = row_start[n + 1];
    float lA = 0.f, lB = 0.f;
    float aA8[8], aB8[8];
#pragma unroll
    for (int c = 0; c < 8; c++) { aA8[c] = 0.f; aB8[c] = 0.f; }

    // this wave's edges: e0+wave, e0+wave+2, ... ; dual chains within
    int j = e0 + wave;
    for (; j + 2 < e1; j += 4) {
        edge_body8(j,     ssrc, ea_h, xlr, c0, wr, xr, attc, lA, aA8);
        edge_body8(j + 2, ssrc, ea_h, xlr, c0, wr, xr, attc, lB, aB8);
    }
    if (j < e1)
        edge_body8(j,     ssrc, ea_h, xlr, c0, wr, xr, attc, lA, aA8);

    // merge partials across the two waves
    __shared__ float sacc[2][HC];
    __shared__ float sl[2][HEADS];
    __shared__ float red[4];
    {
        floatx4 o0 = {aA8[0] + aB8[0], aA8[1] + aB8[1], aA8[2] + aB8[2], aA8[3] + aB8[3]};
        floatx4 o1 = {aA8[4] + aB8[4], aA8[5] + aB8[5], aA8[6] + aB8[6], aA8[7] + aB8[7]};
        *(floatx4*)&sacc[wave][c0] = o0;
        *(floatx4*)&sacc[wave][c0 + 4] = o1;
        if ((lane & 15) == 0) sl[wave][head] = lA + lB;
    }
    __syncthreads();

    // per-thread output channel c = t (0..127): normalized head-mean
    int c = t;
    float v = 0.f;
#pragma unroll
    for (int h = 0; h < HEADS; h++) {
        float lt = sl[0][h] + sl[1][h];
        float invh = 1.f / (lt + 1e-16f);
        v += (sacc[0][h * HID + c] + sacc[1][h * HID + c]) * invh;
    }
    v = 0.25f * v + bgat_l[c];

    float s1 = v, s2 = v * v;
#pragma unroll
    for (int off = 1; off < 64; off <<= 1) {
        s1 += __shfl_xor(s1, off, 64);
        s2 += __shfl_xor(s2, off, 64);
    }
    if (lane == 0) { red[wave * 2] = s1; red[wave * 2 + 1] = s2; }
    __syncthreads();
    s1 = red[0] + red[2];
    s2 = red[1] + red[3];
    float mu = s1 * (1.f / HID);
    float var = s2 * (1.f / HID) - mu * mu;
    float rstd = rsqrtf(var + 1e-5f);
    float y = fmaf(gamma_l[c] * (v - mu), rstd, beta_l[c]);
    y = elu_f(y);
    if (has_res) y += (float)xlr[(size_t)n * NCAT + 1024 + c];
    if (do_pool) atomicAdd(&hsum[(size_t)batch[n] * HID + c], y);
    else hbf_out[(size_t)n * HID + c] = (bf16)y;
}

// ---------------- MLP head ----------------
__global__ __launch_bounds__(128) void k_mlp(const float* __restrict__ hsum,
                                             const int* __restrict__ cnt,
                                             const float* __restrict__ W1, const float* __restrict__ b1,
                                             const float* __restrict__ W2, const float* __restrict__ b2,
                                             const float* __restrict__ W3, const float* __restrict__ b3,
                                             float* __restrict__ out) {
    int g = blockIdx.x, t = threadIdx.x;
    __shared__ float hg[HID], z1[HID], z2[64];
    float invc = 1.f / fmaxf((float)cnt[g], 1.f);
    hg[t] = hsum[(size_t)g * HID + t] * invc;
    __syncthreads();
    float s = b1[t];
#pragma unroll 8
    for (int k = 0; k < HID; k++) s = fmaf(hg[k], W1[k * HID + t], s);
    z1[t] = fmaxf(s, 0.f);
    __syncthreads();
    if (t < 64) {
        float s2 = b2[t];
#pragma unroll 8
        for (int k = 0; k < HID; k++) s2 = fmaf(z1[k], W2[k * 64 + t], s2);
        z2[t] = fmaxf(s2, 0.f);
    }
    __syncthreads();
    if (t < 64) {
        float s3 = z2[t] * W3[t];
#pragma unroll
        for (int off = 1; off < 64; off <<= 1) s3 += __shfl_xor(s3, off, 64);
        if (t == 0) out[g] = s3 + b3[0];
    }
}

// ---------------- host launcher ----------------
extern "C" void kernel_launch(void* const* d_in, const int* in_sizes, int n_in,
                              void* d_out, int out_size, void* d_ws, size_t ws_size,
                              hipStream_t stream) {
    const float* x         = (const float*)d_in[0];
    const int*   ei        = (const int*)  d_in[1];
    const float* edge_attr = (const float*)d_in[2];
    const int*   batch     = (const int*)  d_in[3];
    const float* Win       = (const float*)d_in[4];
    const float* b_in      = (const float*)d_in[5];
    const float* Wl        = (const float*)d_in[6];
    const float* bl        = (const float*)d_in[7];
    const float* Wr        = (const float*)d_in[8];
    const float* br        = (const float*)d_in[9];
    const float* We        = (const float*)d_in[10];
    const float* att       = (const float*)d_in[11];
    const float* b_gat     = (const float*)d_in[12];
    const float* gamma     = (const float*)d_in[13];
    const float* beta      = (const float*)d_in[14];
    const float* Wres      = (const float*)d_in[15];
    const float* bres      = (const float*)d_in[16];
    const float* W1        = (const float*)d_in[17];
    const float* b1        = (const float*)d_in[18];
    const float* W2        = (const float*)d_in[19];
    const float* b2        = (const float*)d_in[20];
    const float* W3        = (const float*)d_in[21];
    const float* b3        = (const float*)d_in[22];
    float* out = (float*)d_out;

    char* ws = (char*)d_ws;
    size_t off = 0;
    auto alloc = [&](size_t bytes) -> void* {
        void* p = ws + off;
        off = (off + bytes + 255) & ~(size_t)255;
        return p;
    };
    bf16*  h_bf    = (bf16*) alloc((size_t)N_NODES * HID * 2);
    bf16*  xlr     = (bf16*) alloc((size_t)N_NODES * NCAT * 2);
    bf16*  WT      = (bf16*) alloc((size_t)LAYERS * NCAT * HID * 2);
    float* bcat    = (float*)alloc((size_t)LAYERS * NCAT * 4);
    f16*   WeH     = (f16*)  alloc((size_t)LAYERS * HC * EDGE_DIM * 2);
    f16*   ea_h    = (f16*)  alloc((size_t)N_EDGES * EDGE_DIM * 2);
    // contiguous zero region: [hsum | cnt | deg]
    char*  zbase   = ws + off;
    float* hsum    = (float*)alloc((size_t)NUM_GRAPHS * HID * 4);
    int*   cnt     = (int*)  alloc((size_t)NUM_GRAPHS * 4);
    int*   deg     = (int*)  alloc((size_t)N_NODES * 4);
    size_t zlen    = (size_t)((ws + off) - zbase);
    int*   rowst   = (int*)  alloc((size_t)(N_NODES + 1) * 4);
    int*   cursor  = (int*)  alloc((size_t)N_NODES * 4);
    int*   ssrc    = (int*)  alloc((size_t)N_EDGES * 4);
    int*   order   = (int*)  alloc((size_t)N_NODES * 4);
    (void)ws_size; // requires ~33 MB

    hipMemsetAsync(zbase, 0, zlen, stream);

    k_prep_all<<<PREP_BLOCKS + DEG_BLOCKS + N_NODES, 128, 0, stream>>>(
        Wl, bl, Wr, br, Wres, bres, We, WT, bcat, WeH,
        ei, batch, deg, cnt, x, Win, b_in, h_bf);
    k_scan<<<1, 1024, 0, stream>>>(deg, rowst, cursor, order);
    k_scatter<<<(N_EDGES + 255) / 256, 256, 0, stream>>>(ei, edge_attr, cursor, ssrc, ea_h);

    const int MG = (N_NODES + 127) / 128;  // 79
    for (int i = 0; i < LAYERS; i++) {
        int ntiles = (i > 0) ? (NCAT / 128) : (1024 / 128);
        k_gemm_mfma<<<dim3(MG, ntiles), 256, 0, stream>>>(
            h_bf, WT + (size_t)i * NCAT * HID, bcat + (size_t)i * NCAT, xlr, N_NODES);
        k_edge_fused<<<N_NODES, 128, 0, stream>>>(
            xlr, ea_h, rowst, ssrc, order,
            WeH + (size_t)i * HC * EDGE_DIM, att + (size_t)i * HEADS * HID,
            b_gat + (size_t)i * HID, gamma + (size_t)i * HID, beta + (size_t)i * HID,
            (i > 0) ? 1 : 0,
            batch, hsum, (i == LAYERS - 1) ? 1 : 0, h_bf);
    }

    k_mlp<<<NUM_GRAPHS, 128, 0, stream>>>(hsum, cnt, W1, b1, W2, b2, W3, b3, out);
}

// Round 16
// 405.875 us; speedup vs baseline: 1.3051x; 1.3051x over previous
//
#include <hip/hip_runtime.h>

#define N_NODES 10000
#define N_EDGES 100000
#define IN_CH 64
#define EDGE_DIM 16
#define HID 128
#define HEADS 4
#define HC 512          // HEADS*HID
#define LAYERS 4
#define NUM_GRAPHS 256
#define NCAT 1152       // 512(xl) + 512(xr) + 128(res) packed cols
#define LDPK 72         // padded LDS stride for 64-elem K-chunk (bf16 elems)

#define PREP_BLOCKS 320 // 10 * LAYERS * 8
#define DEG_BLOCKS 782  // ceil(N_EDGES/128)

typedef __bf16 bf16;
typedef __bf16 bf16x8 __attribute__((ext_vector_type(8)));
typedef __bf16 bf16x4 __attribute__((ext_vector_type(4)));
typedef float floatx4 __attribute__((ext_vector_type(4)));
typedef _Float16 f16;
typedef _Float16 f16x2 __attribute__((ext_vector_type(2)));

__device__ __forceinline__ float elu_f(float x) { return x > 0.f ? x : (__expf(x) - 1.f); }

// ---------------- merged prep: weight repack + degree/count + h0 ----------------
__global__ __launch_bounds__(128) void k_prep_all(
    const float* __restrict__ Wl, const float* __restrict__ bl,
    const float* __restrict__ Wr, const float* __restrict__ br,
    const float* __restrict__ Wres, const float* __restrict__ bres,
    const float* __restrict__ We,
    bf16* __restrict__ WT, float* __restrict__ bcat, f16* __restrict__ WeH,
    const int* __restrict__ ei, const int* __restrict__ batch,
    int* __restrict__ deg, int* __restrict__ cnt,
    const float* __restrict__ x, const float* __restrict__ Win,
    const float* __restrict__ b_in, bf16* __restrict__ h_bf) {
    __shared__ float smem[16 * 129];
    int b = blockIdx.x;
    int t = threadIdx.x;

    if (b < PREP_BLOCKS) {
        int nt = b % 10, i = (b / 10) % LAYERS, z = b / 40;
        if (nt == 9) {
            if (z < 4) {
                int c = z * 128 + t;
                const float* src = We + (size_t)i * EDGE_DIM * HC + c;
                f16 buf[16];
#pragma unroll
                for (int k = 0; k < EDGE_DIM; k++) buf[k] = (f16)src[(size_t)k * HC];
                f16* dst = WeH + ((size_t)i * HC + c) * EDGE_DIM;
                *(uint4*)dst = *(uint4*)buf;
                *(uint4*)(dst + 8) = *(uint4*)(buf + 8);
            }
            return;
        }
        float (*tile)[129] = (float(*)[129])smem;
        int n0 = nt * 128;
        const float* base = nullptr; const float* bsrc = nullptr; int ld = 0;
        if (nt < 4)       { base = Wl + (size_t)i * HID * HC + n0;          bsrc = bl + i * HC + n0;              ld = HC; }
        else if (nt < 8)  { base = Wr + (size_t)i * HID * HC + (n0 - 512);  bsrc = br + i * HC + (n0 - 512);      ld = HC; }
        else if (i > 0)   { base = Wres + (size_t)(i - 1) * HID * HID;      bsrc = bres + (size_t)(i - 1) * HID;  ld = HID; }
        if (base) {
#pragma unroll
            for (int r = 0; r < 16; r++) tile[r][t] = base[(size_t)(z * 16 + r) * ld + t];
        } else {
#pragma unroll
            for (int r = 0; r < 16; r++) tile[r][t] = 0.f;
        }
        __syncthreads();
        int n = n0 + t;
        if (z == 0) bcat[(size_t)i * NCAT + n] = base ? bsrc[t] : 0.f;
        bf16* dst = WT + ((size_t)i * NCAT + n) * HID + z * 16;
#pragma unroll
        for (int kc = 0; kc < 2; kc++) {
            bf16x8 v;
#pragma unroll
            for (int u = 0; u < 8; u++) v[u] = (bf16)tile[kc * 8 + u][t];
            *(bf16x8*)(dst + kc * 8) = v;
        }
    } else if (b < PREP_BLOCKS + DEG_BLOCKS) {
        int e = (b - PREP_BLOCKS) * 128 + t;
        if (e < N_EDGES) atomicAdd(&deg[ei[N_EDGES + e]], 1);
        if (e < N_NODES) atomicAdd(&cnt[batch[e]], 1);
    } else {
        int n = b - (PREP_BLOCKS + DEG_BLOCKS);
        float* xs = smem;
        if (t < IN_CH) xs[t] = x[(size_t)n * IN_CH + t];
        __syncthreads();
        float s = b_in[t];
#pragma unroll 8
        for (int k = 0; k < IN_CH; k++) s = fmaf(xs[k], Win[k * HID + t], s);
        h_bf[(size_t)n * HID + t] = (bf16)elu_f(s);
    }
}

// ---------------- MFMA bf16 GEMM: C[M,NCAT] = A[M,128] @ WT^T + bias ------
__global__ __launch_bounds__(256) void k_gemm_mfma(
    const bf16* __restrict__ A, const bf16* __restrict__ WT,
    const float* __restrict__ bcat, bf16* __restrict__ C, int M) {
    __shared__ __align__(16) unsigned short As[128 * LDPK];
    __shared__ __align__(16) unsigned short Bs[128 * LDPK];
    int t = threadIdx.x;
    int r0 = blockIdx.x * 128, c0 = blockIdx.y * 128;

    int wave = t >> 6, lane = t & 63;
    int wm = wave & 1, wn = wave >> 1;
    int quad = lane >> 4, lm = lane & 15;
    floatx4 zero = {0.f, 0.f, 0.f, 0.f};
    floatx4 acc[4][4];
#pragma unroll
    for (int mi = 0; mi < 4; mi++)
#pragma unroll
        for (int ni = 0; ni < 4; ni++) acc[mi][ni] = zero;

    const unsigned short* Ab = &As[(wm * 64 + lm) * LDPK + quad * 8];
    const unsigned short* Bb = &Bs[(wn * 64 + lm) * LDPK + quad * 8];

    for (int kc = 0; kc < 2; kc++) {
#pragma unroll
        for (int i = 0; i < 4; i++) {
            int idx = t + i * 256;
            int row = idx >> 3;
            int ch = idx & 7;
            int r = r0 + row; if (r >= M) r = M - 1;
            *(uint4*)&As[row * LDPK + ch * 8] =
                *(const uint4*)(A + (size_t)r * HID + kc * 64 + ch * 8);
            *(uint4*)&Bs[row * LDPK + ch * 8] =
                *(const uint4*)(WT + (size_t)(c0 + row) * HID + kc * 64 + ch * 8);
        }
        __syncthreads();
#pragma unroll
        for (int ks = 0; ks < 2; ks++) {
            bf16x8 af[4], bfr[4];
#pragma unroll
            for (int mi = 0; mi < 4; mi++) af[mi] = *(const bf16x8*)(Ab + mi * 16 * LDPK + ks * 32);
#pragma unroll
            for (int ni = 0; ni < 4; ni++) bfr[ni] = *(const bf16x8*)(Bb + ni * 16 * LDPK + ks * 32);
#pragma unroll
            for (int mi = 0; mi < 4; mi++)
#pragma unroll
                for (int ni = 0; ni < 4; ni++)
                    acc[mi][ni] = __builtin_amdgcn_mfma_f32_16x16x32_bf16(bfr[ni], af[mi], acc[mi][ni], 0, 0, 0);
        }
        __syncthreads();
    }

#pragma unroll
    for (int mi = 0; mi < 4; mi++) {
        int row = r0 + wm * 64 + mi * 16 + lm;
        if (row < M) {
            bf16* crow = C + (size_t)row * NCAT;
#pragma unroll
            for (int ni = 0; ni < 4; ni++) {
                int cb = c0 + wn * 64 + ni * 16 + quad * 4;
                float4 b4 = *(const float4*)(bcat + cb);
                floatx4 v = acc[mi][ni];
                bf16x4 o = {(bf16)(v[0] + b4.x), (bf16)(v[1] + b4.y),
                            (bf16)(v[2] + b4.z), (bf16)(v[3] + b4.w)};
                *(bf16x4*)(crow + cb) = o;
            }
        }
    }
}

// shfl-based scan, 4 elems/thread + degree-descending node order (counting sort)
__global__ __launch_bounds__(1024) void k_scan(const int* __restrict__ deg,
                                               int* __restrict__ row_start,
                                               int* __restrict__ cursor,
                                               int* __restrict__ order) {
    __shared__ int wsum[16];
    __shared__ int carry_s;
    __shared__ int hist[64];
    __shared__ int binoff[64];
    int t = threadIdx.x;
    int wave = t >> 6, lane = t & 63;
    if (t == 0) { carry_s = 0; row_start[0] = 0; }
    __syncthreads();
    for (int base = 0; base < N_NODES; base += 4096) {
        int i0 = base + t * 4;
        int v[4];
#pragma unroll
        for (int u = 0; u < 4; u++) v[u] = (i0 + u < N_NODES) ? deg[i0 + u] : 0;
        int tsum = v[0] + v[1] + v[2] + v[3];
        int incl = tsum;
#pragma unroll
        for (int off = 1; off < 64; off <<= 1) {
            int u = __shfl_up(incl, off, 64);
            if (lane >= off) incl += u;
        }
        if (lane == 63) wsum[wave] = incl;
        __syncthreads();
        if (wave == 0) {
            int ws = (lane < 16) ? wsum[lane] : 0;
#pragma unroll
            for (int off = 1; off < 16; off <<= 1) {
                int u = __shfl_up(ws, off, 64);
                if (lane >= off) ws += u;
            }
            if (lane < 16) wsum[lane] = ws;
        }
        __syncthreads();
        int carry = carry_s;
        int chunk_total = wsum[15];
        int p = carry + ((wave == 0) ? 0 : wsum[wave - 1]) + incl - tsum;
#pragma unroll
        for (int u = 0; u < 4; u++) {
            int i = i0 + u;
            if (i < N_NODES) { cursor[i] = p; p += v[u]; row_start[i + 1] = p; }
        }
        __syncthreads();
        if (t == 0) carry_s = carry + chunk_total;
    }

    // ---- counting sort of nodes by degree, DESCENDING (high degree first) ----
    if (t < 64) hist[t] = 0;
    __syncthreads();
    for (int i = t; i < N_NODES; i += 1024) {
        int d = deg[i]; if (d > 63) d = 63;
        atomicAdd(&hist[d], 1);
    }
    __syncthreads();
    if (t < 64) {                       // wave 0 only: suffix sums over 64 bins
        int s = hist[t];
#pragma unroll
        for (int off = 1; off < 64; off <<= 1) {
            int u = __shfl_down(s, off, 64);
            if (t + off >= 64) u = 0;
            s += u;
        }
        binoff[t] = s - hist[t];        // Σ of strictly-greater bins
    }
    __syncthreads();
    for (int i = t; i < N_NODES; i += 1024) {
        int d = deg[i]; if (d > 63) d = 63;
        int pos = atomicAdd(&binoff[d], 1);
        order[pos] = i;
    }
}

// scatter edges into CSR order; permute + f16-convert edge_attr
__global__ void k_scatter(const int* __restrict__ ei, const float* __restrict__ edge_attr,
                          int* __restrict__ cursor,
                          int* __restrict__ ssrc, f16* __restrict__ ea_h) {
    int e = blockIdx.x * blockDim.x + threadIdx.x;
    if (e < N_EDGES) {
        int d = ei[N_EDGES + e];
        int pos = atomicAdd(&cursor[d], 1);
        ssrc[pos] = ei[e];
        const float* s = edge_attr + (size_t)e * EDGE_DIM;
        f16 buf[16];
#pragma unroll
        for (int q = 0; q < 16; q++) buf[q] = (f16)s[q];
        f16* dst = ea_h + (size_t)pos * EDGE_DIM;
        *(uint4*)dst = *(uint4*)buf;
        *(uint4*)(dst + 8) = *(uint4*)(buf + 8);
    }
}

// ---------------- fused edge phase (R14 best shape: 2 waves/node walking all
// edges, 4 ch/lane, f16 dot2, 128B We slice = cheap remat, unroll-2 dual
// chains, degree-descending node scheduling) ----
__global__ __launch_bounds__(128) void k_edge_fused(
    const bf16* __restrict__ xlr, const f16* __restrict__ ea_h,
    const int* __restrict__ row_start, const int* __restrict__ ssrc,
    const int* __restrict__ order,
    const f16* __restrict__ WeH_l, const float* __restrict__ att_l,
    const float* __restrict__ bgat_l, const float* __restrict__ gamma_l,
    const float* __restrict__ beta_l,
    int has_res,
    const int* __restrict__ batch, float* __restrict__ hsum, int do_pool,
    bf16* __restrict__ hbf_out) {
    int n = order[blockIdx.x];
    int t = threadIdx.x;
    int wave = t >> 6;
    int lane = t & 63;
    int c0 = wave * 256 + lane * 4;
    int head = c0 >> 7;

    const f16x2* wr = (const f16x2*)(WeH_l + (size_t)c0 * EDGE_DIM); // 128B contiguous
    float4 att4 = *(const float4*)(att_l + head * HID + (c0 & 127));
    bf16x4 vr = *(const bf16x4*)(xlr + (size_t)n * NCAT + 512 + c0);
    float xr0 = (float)vr[0], xr1 = (float)vr[1], xr2 = (float)vr[2], xr3 = (float)vr[3];

    int e0 = row_start[n], e1 = row_start[n + 1];
    float l0 = 0.f, l1 = 0.f;
    float4 a0 = {0.f, 0.f, 0.f, 0.f}, a1 = {0.f, 0.f, 0.f, 0.f};

    int j = e0;
    for (; j + 1 < e1; j += 2) {
        int s0 = ssrc[j], s1 = ssrc[j + 1];
        const f16x2* eah = (const f16x2*)(ea_h + (size_t)j * EDGE_DIM);
        f16x2 ep0[8], ep1[8];
#pragma unroll
        for (int kp = 0; kp < 8; kp++) ep0[kp] = eah[kp];
#pragma unroll
        for (int kp = 0; kp < 8; kp++) ep1[kp] = eah[8 + kp];
        bf16x4 vl0 = *(const bf16x4*)(xlr + (size_t)s0 * NCAT + c0);
        bf16x4 vl1 = *(const bf16x4*)(xlr + (size_t)s1 * NCAT + c0);

        float p0c0 = 0.f, p0c1 = 0.f, p0c2 = 0.f, p0c3 = 0.f;
        float p1c0 = 0.f, p1c1 = 0.f, p1c2 = 0.f, p1c3 = 0.f;
#pragma unroll
        for (int kp = 0; kp < 8; kp++) {
            p0c0 = __builtin_amdgcn_fdot2(wr[kp],      ep0[kp], p0c0, false);
            p1c0 = __builtin_amdgcn_fdot2(wr[kp],      ep1[kp], p1c0, false);
            p0c1 = __builtin_amdgcn_fdot2(wr[8 + kp],  ep0[kp], p0c1, false);
            p1c1 = __builtin_amdgcn_fdot2(wr[8 + kp],  ep1[kp], p1c1, false);
            p0c2 = __builtin_amdgcn_fdot2(wr[16 + kp], ep0[kp], p0c2, false);
            p1c2 = __builtin_amdgcn_fdot2(wr[16 + kp], ep1[kp], p1c2, false);
            p0c3 = __builtin_amdgcn_fdot2(wr[24 + kp], ep0[kp], p0c3, false);
            p1c3 = __builtin_amdgcn_fdot2(wr[24 + kp], ep1[kp], p1c3, false);
        }
        float x00 = (float)vl0[0], x01 = (float)vl0[1], x02 = (float)vl0[2], x03 = (float)vl0[3];
        float x10 = (float)vl1[0], x11 = (float)vl1[1], x12 = (float)vl1[2], x13 = (float)vl1[3];
        float m00 = x00 + xr0 + p0c0; m00 = fmaxf(m00, 0.2f * m00);
        float m01 = x01 + xr1 + p0c1; m01 = fmaxf(m01, 0.2f * m01);
        float m02 = x02 + xr2 + p0c2; m02 = fmaxf(m02, 0.2f * m02);
        float m03 = x03 + xr3 + p0c3; m03 = fmaxf(m03, 0.2f * m03);
        float m10 = x10 + xr0 + p1c0; m10 = fmaxf(m10, 0.2f * m10);
        float m11 = x11 + xr1 + p1c1; m11 = fmaxf(m11, 0.2f * m11);
        float m12 = x12 + xr2 + p1c2; m12 = fmaxf(m12, 0.2f * m12);
        float m13 = x13 + xr3 + p1c3; m13 = fmaxf(m13, 0.2f * m13);
        float part0 = m00 * att4.x + m01 * att4.y + m02 * att4.z + m03 * att4.w;
        float part1 = m10 * att4.x + m11 * att4.y + m12 * att4.z + m13 * att4.w;
#pragma unroll
        for (int off = 1; off < 32; off <<= 1) {
            part0 += __shfl_xor(part0, off, 64);
            part1 += __shfl_xor(part1, off, 64);
        }
        float p0 = __expf(part0);
        float p1 = __expf(part1);
        l0 += p0; l1 += p1;
        a0.x = fmaf(p0, x00, a0.x); a0.y = fmaf(p0, x01, a0.y);
        a0.z = fmaf(p0, x02, a0.z); a0.w = fmaf(p0, x03, a0.w);
        a1.x = fmaf(p1, x10, a1.x); a1.y = fmaf(p1, x11, a1.y);
        a1.z = fmaf(p1, x12, a1.z); a1.w = fmaf(p1, x13, a1.w);
    }
    if (j < e1) {
        int s0 = ssrc[j];
        const f16x2* eah = (const f16x2*)(ea_h + (size_t)j * EDGE_DIM);
        f16x2 ep0[8];
#pragma unroll
        for (int kp = 0; kp < 8; kp++) ep0[kp] = eah[kp];
        bf16x4 vl0 = *(const bf16x4*)(xlr + (size_t)s0 * NCAT + c0);
        float p0c0 = 0.f, p0c1 = 0.f, p0c2 = 0.f, p0c3 = 0.f;
#pragma unroll
        for (int kp = 0; kp < 8; kp++) {
            p0c0 = __builtin_amdgcn_fdot2(wr[kp],      ep0[kp], p0c0, false);
            p0c1 = __builtin_amdgcn_fdot2(wr[8 + kp],  ep0[kp], p0c1, false);
            p0c2 = __builtin_amdgcn_fdot2(wr[16 + kp], ep0[kp], p0c2, false);
            p0c3 = __builtin_amdgcn_fdot2(wr[24 + kp], ep0[kp], p0c3, false);
        }
        float x00 = (float)vl0[0], x01 = (float)vl0[1], x02 = (float)vl0[2], x03 = (float)vl0[3];
        float m00 = x00 + xr0 + p0c0; m00 = fmaxf(m00, 0.2f * m00);
        float m01 = x01 + xr1 + p0c1; m01 = fmaxf(m01, 0.2f * m01);
        float m02 = x02 + xr2 + p0c2; m02 = fmaxf(m02, 0.2f * m02);
        float m03 = x03 + xr3 + p0c3; m03 = fmaxf(m03, 0.2f * m03);
        float part0 = m00 * att4.x + m01 * att4.y + m02 * att4.z + m03 * att4.w;
#pragma unroll
        for (int off = 1; off < 32; off <<= 1) part0 += __shfl_xor(part0, off, 64);
        float p0 = __expf(part0);
        l0 += p0;
        a0.x = fmaf(p0, x00, a0.x); a0.y = fmaf(p0, x01, a0.y);
        a0.z = fmaf(p0, x02, a0.z); a0.w = fmaf(p0, x03, a0.w);
    }

    float inv = 1.f / (l0 + l1 + 1e-16f);

    __shared__ float sout[HC];
    __shared__ float red[4];
    sout[c0 + 0] = (a0.x + a1.x) * inv;
    sout[c0 + 1] = (a0.y + a1.y) * inv;
    sout[c0 + 2] = (a0.z + a1.z) * inv;
    sout[c0 + 3] = (a0.w + a1.w) * inv;
    __syncthreads();

    int c = t;
    float v = 0.25f * (sout[c] + sout[c + 128] + sout[c + 256] + sout[c + 384]) + bgat_l[c];
    float s1 = v, s2 = v * v;
#pragma unroll
    for (int off = 1; off < 64; off <<= 1) {
        s1 += __shfl_xor(s1, off, 64);
        s2 += __shfl_xor(s2, off, 64);
    }
    if (lane == 0) { red[wave * 2] = s1; red[wave * 2 + 1] = s2; }
    __syncthreads();
    s1 = red[0] + red[2];
    s2 = red[1] + red[3];
    float mu = s1 * (1.f / HID);
    float var = s2 * (1.f / HID) - mu * mu;
    float rstd = rsqrtf(var + 1e-5f);
    float y = fmaf(gamma_l[c] * (v - mu), rstd, beta_l[c]);
    y = elu_f(y);
    if (has_res) y += (float)xlr[(size_t)n * NCAT + 1024 + c];
    if (do_pool) atomicAdd(&hsum[(size_t)batch[n] * HID + c], y);
    else hbf_out[(size_t)n * HID + c] = (bf16)y;
}

// ---------------- MLP head ----------------
__global__ __launch_bounds__(128) void k_mlp(const float* __restrict__ hsum,
                                             const int* __restrict__ cnt,
                                             const float* __restrict__ W1, const float* __restrict__ b1,
                                             const float* __restrict__ W2, const float* __restrict__ b2,
                                             const float* __restrict__ W3, const float* __restrict__ b3,
                                             float* __restrict__ out) {
    int g = blockIdx.x, t = threadIdx.x;
    __shared__ float hg[HID], z1[HID], z2[64];
    float invc = 1.f / fmaxf((float)cnt[g], 1.f);
    hg[t] = hsum[(size_t)g * HID + t] * invc;
    __syncthreads();
    float s = b1[t];
#pragma unroll 8
    for (int k = 0; k < HID; k++) s = fmaf(hg[k], W1[k * HID + t], s);
    z1[t] = fmaxf(s, 0.f);
    __syncthreads();
    if (t < 64) {
        float s2 = b2[t];
#pragma unroll 8
        for (int k = 0; k < HID; k++) s2 = fmaf(z1[k], W2[k * 64 + t], s2);
        z2[t] = fmaxf(s2, 0.f);
    }
    __syncthreads();
    if (t < 64) {
        float s3 = z2[t] * W3[t];
#pragma unroll
        for (int off = 1; off < 64; off <<= 1) s3 += __shfl_xor(s3, off, 64);
        if (t == 0) out[g] = s3 + b3[0];
    }
}

// ---------------- host launcher ----------------
extern "C" void kernel_launch(void* const* d_in, const int* in_sizes, int n_in,
                              void* d_out, int out_size, void* d_ws, size_t ws_size,
                              hipStream_t stream) {
    const float* x         = (const float*)d_in[0];
    const int*   ei        = (const int*)  d_in[1];
    const float* edge_attr = (const float*)d_in[2];
    const int*   batch     = (const int*)  d_in[3];
    const float* Win       = (const float*)d_in[4];
    const float* b_in      = (const float*)d_in[5];
    const float* Wl        = (const float*)d_in[6];
    const float* bl        = (const float*)d_in[7];
    const float* Wr        = (const float*)d_in[8];
    const float* br        = (const float*)d_in[9];
    const float* We        = (const float*)d_in[10];
    const float* att       = (const float*)d_in[11];
    const float* b_gat     = (const float*)d_in[12];
    const float* gamma     = (const float*)d_in[13];
    const float* beta      = (const float*)d_in[14];
    const float* Wres      = (const float*)d_in[15];
    const float* bres      = (const float*)d_in[16];
    const float* W1        = (const float*)d_in[17];
    const float* b1        = (const float*)d_in[18];
    const float* W2        = (const float*)d_in[19];
    const float* b2        = (const float*)d_in[20];
    const float* W3        = (const float*)d_in[21];
    const float* b3        = (const float*)d_in[22];
    float* out = (float*)d_out;

    char* ws = (char*)d_ws;
    size_t off = 0;
    auto alloc = [&](size_t bytes) -> void* {
        void* p = ws + off;
        off = (off + bytes + 255) & ~(size_t)255;
        return p;
    };
    bf16*  h_bf    = (bf16*) alloc((size_t)N_NODES * HID * 2);
    bf16*  xlr     = (bf16*) alloc((size_t)N_NODES * NCAT * 2);
    bf16*  WT      = (bf16*) alloc((size_t)LAYERS * NCAT * HID * 2);
    float* bcat    = (float*)alloc((size_t)LAYERS * NCAT * 4);
    f16*   WeH     = (f16*)  alloc((size_t)LAYERS * HC * EDGE_DIM * 2);
    f16*   ea_h    = (f16*)  alloc((size_t)N_EDGES * EDGE_DIM * 2);
    // contiguous zero region: [hsum | cnt | deg]
    char*  zbase   = ws + off;
    float* hsum    = (float*)alloc((size_t)NUM_GRAPHS * HID * 4);
    int*   cnt     = (int*)  alloc((size_t)NUM_GRAPHS * 4);
    int*   deg     = (int*)  alloc((size_t)N_NODES * 4);
    size_t zlen    = (size_t)((ws + off) - zbase);
    int*   rowst   = (int*)  alloc((size_t)(N_NODES + 1) * 4);
    int*   cursor  = (int*)  alloc((size_t)N_NODES * 4);
    int*   ssrc    = (int*)  alloc((size_t)N_EDGES * 4);
    int*   order   = (int*)  alloc((size_t)N_NODES * 4);
    (void)ws_size; // requires ~33 MB

    hipMemsetAsync(zbase, 0, zlen, stream);

    k_prep_all<<<PREP_BLOCKS + DEG_BLOCKS + N_NODES, 128, 0, stream>>>(
        Wl, bl, Wr, br, Wres, bres, We, WT, bcat, WeH,
        ei, batch, deg, cnt, x, Win, b_in, h_bf);
    k_scan<<<1, 1024, 0, stream>>>(deg, rowst, cursor, order);
    k_scatter<<<(N_EDGES + 255) / 256, 256, 0, stream>>>(ei, edge_attr, cursor, ssrc, ea_h);

    const int MG = (N_NODES + 127) / 128;  // 79
    for (int i = 0; i < LAYERS; i++) {
        int ntiles = (i > 0) ? (NCAT / 128) : (1024 / 128);
        k_gemm_mfma<<<dim3(MG, ntiles), 256, 0, stream>>>(
            h_bf, WT + (size_t)i * NCAT * HID, bcat + (size_t)i * NCAT, xlr, N_NODES);
        k_edge_fused<<<N_NODES, 128, 0, stream>>>(
            xlr, ea_h, rowst, ssrc, order,
            WeH + (size_t)i * HC * EDGE_DIM, att + (size_t)i * HEADS * HID,
            b_gat + (size_t)i * HID, gamma + (size_t)i * HID, beta + (size_t)i * HID,
            (i > 0) ? 1 : 0,
            batch, hsum, (i == LAYERS - 1) ? 1 : 0, h_bf);
    }

    k_mlp<<<NUM_GRAPHS, 128, 0, stream>>>(hsum, cnt, W1, b1, W2, b2, W3, b3, out);
}